// Round 1
// baseline (260.481 us; speedup 1.0000x reference)
//
#include <hip/hip_runtime.h>
#include <hip/hip_bf16.h>

// Shapes: B=16, H=64, W=64, CIN=128, C=256.
// Math identity: softmax(.,axis=1).sum(axis=1) == 1  =>  att == v, q/k unused.
// Pipeline: x = leaky(BN(conv3x3(in))); v = x@wv+bv; y = x+v; out = leaky(LN(y)).

typedef __attribute__((ext_vector_type(8))) short short8x;
typedef __attribute__((ext_vector_type(4))) float floatx4;

__device__ __forceinline__ float bf2f(unsigned short u) {
    union { unsigned int i; float f; } v; v.i = ((unsigned int)u) << 16; return v.f;
}
__device__ __forceinline__ unsigned short f2bf(float f) {
    union { float fl; unsigned int i; } v; v.fl = f;
    return (unsigned short)((v.i + 0x7FFFu + ((v.i >> 16) & 1u)) >> 16);
}
__device__ __forceinline__ float lrelu(float f) { return f > 0.0f ? f : 0.3f * f; }

// ---- prep: transpose+cast weights. cblwt[tap][co][ci], wvt[co][ci] (bf16) ----
__global__ void prep_w(const float* __restrict__ cbl_w, const float* __restrict__ wv,
                       unsigned short* __restrict__ cblwt, unsigned short* __restrict__ wvt) {
    int t = blockIdx.x * 256 + threadIdx.x;
    if (t < 294912) {
        int ci = t & 127, rest = t >> 7;
        int co = rest & 255, tap = rest >> 8;
        // t == (tap*256+co)*128+ci, source is HWIO: ((tap*128)+ci)*256+co
        cblwt[t] = f2bf(cbl_w[(tap * 128 + ci) * 256 + co]);
    } else {
        int u = t - 294912;
        int ci = u & 255, co = u >> 8;   // u == co*256+ci
        wvt[u] = f2bf(wv[ci * 256 + co]);
    }
}

// ---- K1: conv3x3 as implicit GEMM (bf16 MFMA) + bias + BN batch-stat partials ----
// Block = one (b,h) row of 64 pixels x 256 cout. 4 waves, each 64 px x 64 co.
__launch_bounds__(256, 2)
__global__ void conv_bn(const float* __restrict__ inp,
                        const unsigned short* __restrict__ wt,
                        const float* __restrict__ cbl_b,
                        unsigned short* __restrict__ xpre,
                        float* __restrict__ bn_sum, float* __restrict__ bn_sumsq) {
    // 3 rows x 66 cols (pad col -1 and 64) x 128 ci, pixel stride 136 (272B: 4-bank step, 16B aligned)
    __shared__ unsigned short a_lds[3 * 66 * 136];
    const int h = blockIdx.x, b = blockIdx.y;
    const int tid = threadIdx.x;

    for (int idx = tid; idx < 3 * 66 * 16; idx += 256) {
        const int c8 = idx & 15;
        const int px = idx >> 4;
        const int ix = px % 66;
        const int iy = px / 66;
        const int gy = h + iy - 1;
        const int gx = ix - 1;
        unsigned short u[8] = {0, 0, 0, 0, 0, 0, 0, 0};
        if (gy >= 0 && gy < 64 && gx >= 0 && gx < 64) {
            const float4* p = reinterpret_cast<const float4*>(
                inp + (((b * 64 + gy) * 64 + gx) * 128 + c8 * 8));
            const float4 f0 = p[0], f1 = p[1];
            u[0] = f2bf(f0.x); u[1] = f2bf(f0.y); u[2] = f2bf(f0.z); u[3] = f2bf(f0.w);
            u[4] = f2bf(f1.x); u[5] = f2bf(f1.y); u[6] = f2bf(f1.z); u[7] = f2bf(f1.w);
        }
        union { uint4 q; unsigned short s[8]; } pk;
        #pragma unroll
        for (int j = 0; j < 8; ++j) pk.s[j] = u[j];
        *reinterpret_cast<uint4*>(&a_lds[(iy * 66 + ix) * 136 + c8 * 8]) = pk.q;
    }
    __syncthreads();

    const int lane = tid & 63, wave = tid >> 6;
    const int l15 = lane & 15, l4 = lane >> 4;
    const int co_base = wave * 64;

    floatx4 acc[4][4];
    #pragma unroll
    for (int m = 0; m < 4; ++m)
        #pragma unroll
        for (int n = 0; n < 4; ++n)
            acc[m][n] = (floatx4){0.f, 0.f, 0.f, 0.f};

    for (int dy = 0; dy < 3; ++dy) {
        #pragma unroll
        for (int dx = 0; dx < 3; ++dx) {
            const unsigned short* wtap = wt + (dy * 3 + dx) * 256 * 128;
            #pragma unroll
            for (int kk = 0; kk < 4; ++kk) {
                const int kb = kk * 32 + l4 * 8;
                short8x a[4], bb[4];
                #pragma unroll
                for (int m = 0; m < 4; ++m)
                    a[m] = *reinterpret_cast<const short8x*>(
                        &a_lds[(dy * 66 + m * 16 + l15 + dx) * 136 + kb]);
                #pragma unroll
                for (int n = 0; n < 4; ++n)
                    bb[n] = *reinterpret_cast<const short8x*>(
                        wtap + (co_base + n * 16 + l15) * 128 + kb);
                #pragma unroll
                for (int m = 0; m < 4; ++m)
                    #pragma unroll
                    for (int n = 0; n < 4; ++n)
                        acc[m][n] = __builtin_amdgcn_mfma_f32_16x16x32_bf16(
                            a[m], bb[n], acc[m][n], 0, 0, 0);
            }
        }
    }

    // epilogue: +bias, store bf16 x_pre, per-channel partial sums for BN stats
    #pragma unroll
    for (int n = 0; n < 4; ++n) {
        const int co = co_base + n * 16 + l15;
        const float bias = cbl_b[co];
        float s = 0.f, s2 = 0.f;
        #pragma unroll
        for (int m = 0; m < 4; ++m) {
            #pragma unroll
            for (int r = 0; r < 4; ++r) {
                const int w = m * 16 + l4 * 4 + r;    // C/D: row=(lane>>4)*4+reg
                const float val = acc[m][n][r] + bias;
                xpre[((b * 4096 + h * 64 + w) * 256) + co] = f2bf(val);
                s += val; s2 += val * val;
            }
        }
        s += __shfl_xor(s, 16); s += __shfl_xor(s, 32);
        s2 += __shfl_xor(s2, 16); s2 += __shfl_xor(s2, 32);
        if (l4 == 0) {
            atomicAdd(&bn_sum[co], s);
            atomicAdd(&bn_sumsq[co], s2);
        }
    }
}

// ---- K2: BN-apply + leaky -> x tile in LDS; v = x@wv (MFMA); y = x+v+bv;
//          store y bf16; per-sample LN partial sums ----
__launch_bounds__(256, 2)
__global__ void fused_mid(const unsigned short* __restrict__ xpre,
                          const unsigned short* __restrict__ wvt,
                          const float* __restrict__ bv,
                          const float* __restrict__ bn_sum, const float* __restrict__ bn_sumsq,
                          const float* __restrict__ bn_gamma, const float* __restrict__ bn_beta,
                          unsigned short* __restrict__ yws,
                          float* __restrict__ ln_sum, float* __restrict__ ln_sumsq) {
    __shared__ unsigned short x_lds[64 * 264];  // 64 px x 256 c, +8 pad (528B stride)
    __shared__ float s_scale[256], s_shift[256];
    __shared__ float s_red[8];
    const int h = blockIdx.x, b = blockIdx.y;
    const int tid = threadIdx.x;

    {
        const float mean = bn_sum[tid] * (1.0f / 65536.0f);
        const float var  = bn_sumsq[tid] * (1.0f / 65536.0f) - mean * mean;
        const float sc = bn_gamma[tid] * rsqrtf(var + 1e-3f);
        s_scale[tid] = sc;
        s_shift[tid] = bn_beta[tid] - mean * sc;
    }
    __syncthreads();

    float scv[8], shv[8];
    {
        const int c0 = (tid & 31) * 8;
        #pragma unroll
        for (int j = 0; j < 8; ++j) { scv[j] = s_scale[c0 + j]; shv[j] = s_shift[c0 + j]; }
    }

    const unsigned short* xrow = xpre + (b * 4096 + h * 64) * 256;
    for (int idx = tid; idx < 64 * 32; idx += 256) {
        const int c8 = idx & 31;   // == tid&31, scv/shv stay valid
        const int px = idx >> 5;
        union { uint4 q; unsigned short s[8]; } iv, ov;
        iv.q = *reinterpret_cast<const uint4*>(xrow + px * 256 + c8 * 8);
        #pragma unroll
        for (int j = 0; j < 8; ++j) {
            const float f = fmaf(bf2f(iv.s[j]), scv[j], shv[j]);
            ov.s[j] = f2bf(lrelu(f));
        }
        *reinterpret_cast<uint4*>(&x_lds[px * 264 + c8 * 8]) = ov.q;
    }
    __syncthreads();

    const int lane = tid & 63, wave = tid >> 6;
    const int l15 = lane & 15, l4 = lane >> 4;
    const int co_base = wave * 64;

    floatx4 acc[4][4];
    #pragma unroll
    for (int m = 0; m < 4; ++m)
        #pragma unroll
        for (int n = 0; n < 4; ++n)
            acc[m][n] = (floatx4){0.f, 0.f, 0.f, 0.f};

    #pragma unroll
    for (int kk = 0; kk < 8; ++kk) {
        const int kb = kk * 32 + l4 * 8;
        short8x a[4], bb[4];
        #pragma unroll
        for (int m = 0; m < 4; ++m)
            a[m] = *reinterpret_cast<const short8x*>(&x_lds[(m * 16 + l15) * 264 + kb]);
        #pragma unroll
        for (int n = 0; n < 4; ++n)
            bb[n] = *reinterpret_cast<const short8x*>(wvt + (co_base + n * 16 + l15) * 256 + kb);
        #pragma unroll
        for (int m = 0; m < 4; ++m)
            #pragma unroll
            for (int n = 0; n < 4; ++n)
                acc[m][n] = __builtin_amdgcn_mfma_f32_16x16x32_bf16(
                    a[m], bb[n], acc[m][n], 0, 0, 0);
    }

    float ls = 0.f, ls2 = 0.f;
    #pragma unroll
    for (int n = 0; n < 4; ++n) {
        const int co = co_base + n * 16 + l15;
        const float bias = bv[co];
        #pragma unroll
        for (int m = 0; m < 4; ++m) {
            #pragma unroll
            for (int r = 0; r < 4; ++r) {
                const int px = m * 16 + l4 * 4 + r;
                const float y = bf2f(x_lds[px * 264 + co]) + acc[m][n][r] + bias;
                yws[(b * 4096 + h * 64 + px) * 256 + co] = f2bf(y);
                ls += y; ls2 += y * y;
            }
        }
    }
    #pragma unroll
    for (int off = 32; off > 0; off >>= 1) {
        ls += __shfl_xor(ls, off);
        ls2 += __shfl_xor(ls2, off);
    }
    if (lane == 0) { s_red[wave] = ls; s_red[wave + 4] = ls2; }
    __syncthreads();
    if (tid == 0) {
        atomicAdd(&ln_sum[b], s_red[0] + s_red[1] + s_red[2] + s_red[3]);
        atomicAdd(&ln_sumsq[b], s_red[4] + s_red[5] + s_red[6] + s_red[7]);
    }
}

// ---- K3: LayerNorm (per-sample stats) + per-element affine + leaky -> f32 out ----
__global__ void final_ln(const unsigned short* __restrict__ yws,
                         const float* __restrict__ ln_sum, const float* __restrict__ ln_sumsq,
                         const float* __restrict__ ln_gamma, const float* __restrict__ ln_beta,
                         float* __restrict__ out) {
    const int i = blockIdx.x * 256 + threadIdx.x;
    const int e = i << 2;
    if (e >= 16777216) return;
    const int b = e >> 20;           // 1048576 elems per sample
    const int g = e & 1048575;       // index into (H,W,C) affine params
    const float mean = ln_sum[b] * (1.0f / 1048576.0f);
    const float var  = ln_sumsq[b] * (1.0f / 1048576.0f) - mean * mean;
    const float inv  = rsqrtf(var + 1e-3f);
    const ushort4 yv = *reinterpret_cast<const ushort4*>(yws + e);
    const float4 gm = reinterpret_cast<const float4*>(ln_gamma)[g >> 2];
    const float4 bt = reinterpret_cast<const float4*>(ln_beta)[g >> 2];
    float4 o;
    o.x = lrelu((bf2f(yv.x) - mean) * inv * gm.x + bt.x);
    o.y = lrelu((bf2f(yv.y) - mean) * inv * gm.y + bt.y);
    o.z = lrelu((bf2f(yv.z) - mean) * inv * gm.z + bt.z);
    o.w = lrelu((bf2f(yv.w) - mean) * inv * gm.w + bt.w);
    reinterpret_cast<float4*>(out)[i] = o;
}

extern "C" void kernel_launch(void* const* d_in, const int* in_sizes, int n_in,
                              void* d_out, int out_size, void* d_ws, size_t ws_size,
                              hipStream_t stream) {
    (void)in_sizes; (void)n_in; (void)out_size; (void)ws_size;
    const float* inputs   = (const float*)d_in[0];
    const float* cbl_w    = (const float*)d_in[1];
    const float* cbl_b    = (const float*)d_in[2];
    const float* bn_gamma = (const float*)d_in[3];
    const float* bn_beta  = (const float*)d_in[4];
    // d_in[5..8] (wq,bq,wk,bk) are mathematically dead: softmax-col-sums == 1
    const float* wv       = (const float*)d_in[9];
    const float* bv       = (const float*)d_in[10];
    const float* ln_gamma = (const float*)d_in[11];
    const float* ln_beta  = (const float*)d_in[12];
    float* out = (float*)d_out;

    char* ws = (char*)d_ws;
    unsigned short* xpre  = (unsigned short*)(ws + 0);          // 32 MiB
    unsigned short* yws   = (unsigned short*)(ws + 33554432);   // 32 MiB
    unsigned short* cblwt = (unsigned short*)(ws + 67108864);   // 576 KiB
    unsigned short* wvt   = (unsigned short*)(ws + 67698688);   // 128 KiB
    float* accum          = (float*)(ws + 67829760);            // 544 floats
    float* bn_sum   = accum;
    float* bn_sumsq = accum + 256;
    float* ln_sum   = accum + 512;
    float* ln_sumsq = accum + 528;

    hipMemsetAsync(accum, 0, 544 * sizeof(float), stream);
    prep_w<<<1408, 256, 0, stream>>>(cbl_w, wv, cblwt, wvt);
    conv_bn<<<dim3(64, 16), 256, 0, stream>>>(inputs, cblwt, cbl_b, xpre, bn_sum, bn_sumsq);
    fused_mid<<<dim3(64, 16), 256, 0, stream>>>(xpre, wvt, bv, bn_sum, bn_sumsq,
                                                bn_gamma, bn_beta, yws, ln_sum, ln_sumsq);
    final_ln<<<16384, 256, 0, stream>>>(yws, ln_sum, ln_sumsq, ln_gamma, ln_beta, out);
}

// Round 2
// 205.457 us; speedup vs baseline: 1.2678x; 1.2678x over previous
//
#include <hip/hip_runtime.h>
#include <hip/hip_bf16.h>

// Shapes: B=16, H=64, W=64, CIN=128, C=256.
// Math identity: softmax(.,axis=1).sum(axis=1) == 1  =>  att == v, q/k unused.
// Pipeline: x = leaky(BN(conv3x3(in))); v = x@wv+bv; y = x+v; out = leaky(LN(y)).

typedef __attribute__((ext_vector_type(8))) short short8x;
typedef __attribute__((ext_vector_type(4))) float floatx4;

__device__ __forceinline__ float bf2f(unsigned short u) {
    union { unsigned int i; float f; } v; v.i = ((unsigned int)u) << 16; return v.f;
}
__device__ __forceinline__ unsigned short f2bf(float f) {
    union { float fl; unsigned int i; } v; v.fl = f;
    return (unsigned short)((v.i + 0x7FFFu + ((v.i >> 16) & 1u)) >> 16);
}
__device__ __forceinline__ float lrelu(float f) { return f > 0.0f ? f : 0.3f * f; }

// ---- prep: transpose+cast weights. cblwt[tap][co][ci], wvt[co][ci] (bf16) ----
__global__ void prep_w(const float* __restrict__ cbl_w, const float* __restrict__ wv,
                       unsigned short* __restrict__ cblwt, unsigned short* __restrict__ wvt) {
    int t = blockIdx.x * 256 + threadIdx.x;
    if (t < 294912) {
        int ci = t & 127, rest = t >> 7;
        int co = rest & 255, tap = rest >> 8;
        cblwt[t] = f2bf(cbl_w[(tap * 128 + ci) * 256 + co]);
    } else {
        int u = t - 294912;
        int ci = u & 255, co = u >> 8;
        wvt[u] = f2bf(wv[ci * 256 + co]);
    }
}

// ---- K1: conv3x3 implicit GEMM. Block = 4 rows (256 px) x 256 co, 8 waves.
//      A (6 input rows, bf16) XOR-swizzled in LDS; B (weights) triple-buffered
//      16KB stages via global_load_lds with counted vmcnt (never 0 in loop). ----
__launch_bounds__(512, 2)
__global__ void conv_bn(const float* __restrict__ inp,
                        const unsigned short* __restrict__ wt,
                        const float* __restrict__ cbl_b,
                        unsigned short* __restrict__ xpre,
                        float* __restrict__ bn_sum, float* __restrict__ bn_sumsq) {
    __shared__ unsigned short a_sh[50688];   // 6*66 px * 128 ci, swizzled, 101376 B
    __shared__ unsigned short b_sh[24576];   // 3 bufs * 256 co * 32 ci, 49152 B
    const int h0 = blockIdx.x * 4;
    const int b  = blockIdx.y;
    const int tid = threadIdx.x;
    const int lane = tid & 63, wave = tid >> 6;
    const int l15 = lane & 15, l4 = lane >> 4;
    const int wave_m = wave >> 2, wave_n = wave & 3;

    // ---- stage A: rows h0-1..h0+4, cols -1..64, fp32 -> bf16, swizzled ----
    for (int idx = tid; idx < 6336; idx += 512) {
        const int c  = idx & 15;          // 16B chunk (8 ci)
        const int p  = idx >> 4;
        const int px = p % 66;
        const int r  = p / 66;
        const int gy = h0 + r - 1;
        const int gx = px - 1;
        union { uint4 q; unsigned short s[8]; } pk;
        if ((unsigned)gy < 64u && (unsigned)gx < 64u) {
            const float4* sp = reinterpret_cast<const float4*>(
                inp + (((b * 64 + gy) * 64 + gx) * 128 + c * 8));
            const float4 f0 = sp[0], f1 = sp[1];
            pk.s[0]=f2bf(f0.x); pk.s[1]=f2bf(f0.y); pk.s[2]=f2bf(f0.z); pk.s[3]=f2bf(f0.w);
            pk.s[4]=f2bf(f1.x); pk.s[5]=f2bf(f1.y); pk.s[6]=f2bf(f1.z); pk.s[7]=f2bf(f1.w);
        } else {
            pk.q = make_uint4(0u, 0u, 0u, 0u);
        }
        const int byte = ((r * 66 + px) * 256 + c * 16) ^ ((px & 7) << 4);
        *reinterpret_cast<uint4*>(reinterpret_cast<char*>(a_sh) + byte) = pk.q;
    }
    __syncthreads();

    floatx4 acc[8][4];
    #pragma unroll
    for (int m = 0; m < 8; ++m)
        #pragma unroll
        for (int n = 0; n < 4; ++n)
            acc[m][n] = (floatx4){0.f, 0.f, 0.f, 0.f};

    const int line0 = wave * 2;
    auto b_issue = [&](int tap, int kk, int buf) {
        #pragma unroll
        for (int j = 0; j < 2; ++j) {
            const int co = (line0 + j) * 16 + (lane >> 2);
            const unsigned short* src = wt + ((tap * 256 + co) * 128 + kk * 32 + (lane & 3) * 8);
            unsigned short* dst = &b_sh[buf * 8192 + (line0 + j) * 512];  // wave-uniform base
            __builtin_amdgcn_global_load_lds(
                (const __attribute__((address_space(1))) void*)src,
                (__attribute__((address_space(3))) void*)dst, 16, 0, 0);
        }
    };
    auto c_step = [&](int dy, int dx, int kk, int buf) {
        short8x av[8], bbv[4];
        const char* bb = reinterpret_cast<const char*>(b_sh) + buf * 16384;
        #pragma unroll
        for (int n = 0; n < 4; ++n)
            bbv[n] = *reinterpret_cast<const short8x*>(
                bb + (wave_n * 64 + n * 16 + l15) * 64 + l4 * 16);
        const char* ab = reinterpret_cast<const char*>(a_sh);
        #pragma unroll
        for (int m = 0; m < 8; ++m) {
            const int col = (m & 3) * 16 + l15 + dx;
            const int row = wave_m * 2 + (m >> 2) + dy;
            const int byte = ((row * 66 + col) * 256 + kk * 64 + l4 * 16) ^ ((col & 7) << 4);
            av[m] = *reinterpret_cast<const short8x*>(ab + byte);
        }
        #pragma unroll
        for (int m = 0; m < 8; ++m)
            #pragma unroll
            for (int n = 0; n < 4; ++n)
                acc[m][n] = __builtin_amdgcn_mfma_f32_16x16x32_bf16(
                    av[m], bbv[n], acc[m][n], 0, 0, 0);
    };

    // prologue: stages 0,1 in flight
    b_issue(0, 0, 0);
    b_issue(0, 1, 1);

    // main loop: s = tap*4+kk in 0..31. Per iter: wait stage s (leave s+1 in
    // flight), barrier (cross-wave visibility + anti-dep), compute, issue s+2.
    int buf = 0;
    for (int tap = 0; tap < 8; ++tap) {
        const int dy = tap / 3, dx = tap % 3;
        #pragma unroll
        for (int kk = 0; kk < 4; ++kk) {
            asm volatile("s_waitcnt vmcnt(2)" ::: "memory");
            __builtin_amdgcn_s_barrier();
            __builtin_amdgcn_sched_barrier(0);
            c_step(dy, dx, kk, buf);
            const int ntap = tap + (kk >> 1);          // stage s+2
            const int nkk  = (kk + 2) & 3;
            const int nbuf = (buf == 0) ? 2 : buf - 1; // (s+2)%3
            b_issue(ntap, nkk, nbuf);
            buf = (buf == 2) ? 0 : buf + 1;
        }
    }
    // tail: tap 8 (dy=2,dx=2), s=32..35; buf==2 here (32%3)
    asm volatile("s_waitcnt vmcnt(2)" ::: "memory");
    __builtin_amdgcn_s_barrier();
    __builtin_amdgcn_sched_barrier(0);
    c_step(2, 2, 0, 2);
    b_issue(8, 2, 1);
    asm volatile("s_waitcnt vmcnt(2)" ::: "memory");
    __builtin_amdgcn_s_barrier();
    __builtin_amdgcn_sched_barrier(0);
    c_step(2, 2, 1, 0);
    b_issue(8, 3, 2);
    asm volatile("s_waitcnt vmcnt(2)" ::: "memory");
    __builtin_amdgcn_s_barrier();
    __builtin_amdgcn_sched_barrier(0);
    c_step(2, 2, 2, 1);
    asm volatile("s_waitcnt vmcnt(0)" ::: "memory");
    __builtin_amdgcn_s_barrier();
    __builtin_amdgcn_sched_barrier(0);
    c_step(2, 2, 3, 2);

    // epilogue: +bias, store bf16 x_pre, BN partial sums
    const int pbase = b * 4096 + h0 * 64;
    #pragma unroll
    for (int n = 0; n < 4; ++n) {
        const int co = wave_n * 64 + n * 16 + l15;
        const float bias = cbl_b[co];
        float s = 0.f, s2 = 0.f;
        #pragma unroll
        for (int m = 0; m < 8; ++m) {
            #pragma unroll
            for (int r = 0; r < 4; ++r) {
                const int p = wave_m * 128 + m * 16 + l4 * 4 + r;
                const float val = acc[m][n][r] + bias;
                xpre[(pbase + p) * 256 + co] = f2bf(val);
                s += val; s2 += val * val;
            }
        }
        s  += __shfl_xor(s, 16);  s  += __shfl_xor(s, 32);
        s2 += __shfl_xor(s2, 16); s2 += __shfl_xor(s2, 32);
        if (l4 == 0) {
            atomicAdd(&bn_sum[co], s);
            atomicAdd(&bn_sumsq[co], s2);
        }
    }
}

// ---- K2: BN-apply + leaky -> 256px x-tile in LDS (swizzled); v = x@wv (MFMA,
//      B from L2 with reg prefetch); y = x+v+bv; store bf16; LN partials. ----
__launch_bounds__(512, 2)
__global__ void fused_mid(const unsigned short* __restrict__ xpre,
                          const unsigned short* __restrict__ wvt,
                          const float* __restrict__ bv,
                          const float* __restrict__ bn_sum, const float* __restrict__ bn_sumsq,
                          const float* __restrict__ bn_gamma, const float* __restrict__ bn_beta,
                          unsigned short* __restrict__ yws,
                          float* __restrict__ ln_sum, float* __restrict__ ln_sumsq) {
    __shared__ unsigned short x_sh[65536];   // 256 px x 256 ci, swizzled, 131072 B
    __shared__ float s_scale[256], s_shift[256];
    __shared__ float s_red[16];
    const int tid = threadIdx.x;
    const int pbase = blockIdx.y * 4096 + blockIdx.x * 256;  // 256 contiguous pixels

    if (tid < 256) {
        const float mean = bn_sum[tid] * (1.0f / 65536.0f);
        const float var  = bn_sumsq[tid] * (1.0f / 65536.0f) - mean * mean;
        const float sc = bn_gamma[tid] * rsqrtf(var + 1e-3f);
        s_scale[tid] = sc;
        s_shift[tid] = bn_beta[tid] - mean * sc;
    }
    __syncthreads();

    float scv[8], shv[8];
    {
        const int c0 = (tid & 31) * 8;
        #pragma unroll
        for (int j = 0; j < 8; ++j) { scv[j] = s_scale[c0 + j]; shv[j] = s_shift[c0 + j]; }
    }
    // stage x (BN-apply + leaky), 8192 chunks of 16B
    #pragma unroll 4
    for (int i = 0; i < 16; ++i) {
        const int idx = tid + i * 512;
        const int cc = idx & 31;        // == tid&31, scv/shv valid
        const int p  = idx >> 5;
        union { uint4 q; unsigned short s[8]; } iv, ov;
        iv.q = *reinterpret_cast<const uint4*>(xpre + (pbase + p) * 256 + cc * 8);
        #pragma unroll
        for (int j = 0; j < 8; ++j) {
            const float f = fmaf(bf2f(iv.s[j]), scv[j], shv[j]);
            ov.s[j] = f2bf(lrelu(f));
        }
        const int byte = (p * 512 + cc * 16) ^ ((p & 7) << 4);
        *reinterpret_cast<uint4*>(reinterpret_cast<char*>(x_sh) + byte) = ov.q;
    }
    __syncthreads();

    const int lane = tid & 63, wave = tid >> 6;
    const int l15 = lane & 15, l4 = lane >> 4;
    const int wave_m = wave >> 2, wave_n = wave & 3;

    floatx4 acc[8][4];
    #pragma unroll
    for (int m = 0; m < 8; ++m)
        #pragma unroll
        for (int n = 0; n < 4; ++n)
            acc[m][n] = (floatx4){0.f, 0.f, 0.f, 0.f};

    short8x bcur[4], bnxt[4];
    #pragma unroll
    for (int n = 0; n < 4; ++n)
        bcur[n] = *reinterpret_cast<const short8x*>(
            wvt + (wave_n * 64 + n * 16 + l15) * 256 + l4 * 8);

    const char* xb = reinterpret_cast<const char*>(x_sh);
    #pragma unroll
    for (int kk = 0; kk < 8; ++kk) {
        if (kk < 7) {
            #pragma unroll
            for (int n = 0; n < 4; ++n)
                bnxt[n] = *reinterpret_cast<const short8x*>(
                    wvt + (wave_n * 64 + n * 16 + l15) * 256 + (kk + 1) * 32 + l4 * 8);
        }
        short8x av[8];
        #pragma unroll
        for (int m = 0; m < 8; ++m) {
            const int p = wave_m * 128 + m * 16 + l15;
            const int byte = (p * 512 + kk * 64 + l4 * 16) ^ ((p & 7) << 4);
            av[m] = *reinterpret_cast<const short8x*>(xb + byte);
        }
        #pragma unroll
        for (int m = 0; m < 8; ++m)
            #pragma unroll
            for (int n = 0; n < 4; ++n)
                acc[m][n] = __builtin_amdgcn_mfma_f32_16x16x32_bf16(
                    av[m], bcur[n], acc[m][n], 0, 0, 0);
        if (kk < 7) {
            #pragma unroll
            for (int n = 0; n < 4; ++n) bcur[n] = bnxt[n];
        }
    }

    float ls = 0.f, ls2 = 0.f;
    #pragma unroll
    for (int n = 0; n < 4; ++n) {
        const int co = wave_n * 64 + n * 16 + l15;
        const float bias = bv[co];
        #pragma unroll
        for (int m = 0; m < 8; ++m) {
            #pragma unroll
            for (int r = 0; r < 4; ++r) {
                const int p = wave_m * 128 + m * 16 + l4 * 4 + r;
                const float xv = bf2f(*reinterpret_cast<const unsigned short*>(
                    xb + ((p * 512 + co * 2) ^ ((p & 7) << 4))));
                const float y = xv + acc[m][n][r] + bias;
                yws[(pbase + p) * 256 + co] = f2bf(y);
                ls += y; ls2 += y * y;
            }
        }
    }
    #pragma unroll
    for (int off = 32; off > 0; off >>= 1) {
        ls += __shfl_xor(ls, off);
        ls2 += __shfl_xor(ls2, off);
    }
    if (lane == 0) { s_red[wave] = ls; s_red[wave + 8] = ls2; }
    __syncthreads();
    if (tid == 0) {
        float a = 0.f, c = 0.f;
        #pragma unroll
        for (int w = 0; w < 8; ++w) { a += s_red[w]; c += s_red[w + 8]; }
        atomicAdd(&ln_sum[blockIdx.y], a);
        atomicAdd(&ln_sumsq[blockIdx.y], c);
    }
}

// ---- K3: LayerNorm (per-sample stats) + per-element affine + leaky -> f32 out ----
__global__ void final_ln(const unsigned short* __restrict__ yws,
                         const float* __restrict__ ln_sum, const float* __restrict__ ln_sumsq,
                         const float* __restrict__ ln_gamma, const float* __restrict__ ln_beta,
                         float* __restrict__ out) {
    const int i = blockIdx.x * 256 + threadIdx.x;
    const int e = i << 2;
    if (e >= 16777216) return;
    const int b = e >> 20;
    const int g = e & 1048575;
    const float mean = ln_sum[b] * (1.0f / 1048576.0f);
    const float var  = ln_sumsq[b] * (1.0f / 1048576.0f) - mean * mean;
    const float inv  = rsqrtf(var + 1e-3f);
    const ushort4 yv = *reinterpret_cast<const ushort4*>(yws + e);
    const float4 gm = reinterpret_cast<const float4*>(ln_gamma)[g >> 2];
    const float4 bt = reinterpret_cast<const float4*>(ln_beta)[g >> 2];
    float4 o;
    o.x = lrelu((bf2f(yv.x) - mean) * inv * gm.x + bt.x);
    o.y = lrelu((bf2f(yv.y) - mean) * inv * gm.y + bt.y);
    o.z = lrelu((bf2f(yv.z) - mean) * inv * gm.z + bt.z);
    o.w = lrelu((bf2f(yv.w) - mean) * inv * gm.w + bt.w);
    reinterpret_cast<float4*>(out)[i] = o;
}

extern "C" void kernel_launch(void* const* d_in, const int* in_sizes, int n_in,
                              void* d_out, int out_size, void* d_ws, size_t ws_size,
                              hipStream_t stream) {
    (void)in_sizes; (void)n_in; (void)out_size; (void)ws_size;
    const float* inputs   = (const float*)d_in[0];
    const float* cbl_w    = (const float*)d_in[1];
    const float* cbl_b    = (const float*)d_in[2];
    const float* bn_gamma = (const float*)d_in[3];
    const float* bn_beta  = (const float*)d_in[4];
    // d_in[5..8] (wq,bq,wk,bk) are mathematically dead: softmax-col-sums == 1
    const float* wv       = (const float*)d_in[9];
    const float* bv       = (const float*)d_in[10];
    const float* ln_gamma = (const float*)d_in[11];
    const float* ln_beta  = (const float*)d_in[12];
    float* out = (float*)d_out;

    char* ws = (char*)d_ws;
    unsigned short* xpre  = (unsigned short*)(ws + 0);          // 32 MiB
    unsigned short* yws   = (unsigned short*)(ws + 33554432);   // 32 MiB
    unsigned short* cblwt = (unsigned short*)(ws + 67108864);   // 576 KiB
    unsigned short* wvt   = (unsigned short*)(ws + 67698688);   // 128 KiB
    float* accum          = (float*)(ws + 67829760);            // 544 floats
    float* bn_sum   = accum;
    float* bn_sumsq = accum + 256;
    float* ln_sum   = accum + 512;
    float* ln_sumsq = accum + 528;

    hipMemsetAsync(accum, 0, 544 * sizeof(float), stream);
    prep_w<<<1408, 256, 0, stream>>>(cbl_w, wv, cblwt, wvt);
    conv_bn<<<dim3(16, 16), 512, 0, stream>>>(inputs, cblwt, cbl_b, xpre, bn_sum, bn_sumsq);
    fused_mid<<<dim3(16, 16), 512, 0, stream>>>(xpre, wvt, bv, bn_sum, bn_sumsq,
                                                bn_gamma, bn_beta, yws, ln_sum, ln_sumsq);
    final_ln<<<16384, 256, 0, stream>>>(yws, ln_sum, ln_sumsq, ln_gamma, ln_beta, out);
}